// Round 7
// baseline (28.762 us; speedup 1.0000x reference)
//
#include <hip/hip_runtime.h>

#define NSCENE 64
#define NPTS   16384
#define SIN    256
#define SH     128
#define SOUT   128
#define TILE_P 32

// ---- workspace layout (bytes) ----
#define WS_PARTIAL 0              // 64*64 int (per-block partial histograms)
#define WS_OFFSETS 16384          // 65 int
#define WS_PERM    17408          // 16384 int
#define WS_WBF16   82944          // 5,242,880 shorts = 10,485,760 B (fragment-ordered)
#define W0_ELEMS   (NSCENE*SH*SIN)    // 2,097,152 (32768/scene)
#define W1_ELEMS   (NSCENE*SOUT*SH)   // 1,048,576 (16384/scene)
#define W2_ELEMS   (NSCENE*SOUT*SIN)  // 2,097,152 (32768/scene)
#define WTOT       (W0_ELEMS+W1_ELEMS+W2_ELEMS)  // 5,242,880
#define CONV_BLOCKS (WTOT/2048)   // 2560 blocks x 256 thr x 8 elems
// fragment-order within a scene region: [w][ks][lane][8]  (elems)
//   L0/L2: w<<12 | ks<<9 | lane<<3 (8 ks)   L1: w<<11 | ks<<9 | lane<<3 (4 ks)
// lane l supplies W[row = w*16 + (l&15)][k = ks*32 + (l>>4)*8 .. +8]

typedef __attribute__((ext_vector_type(8))) short bf16x8;
typedef __attribute__((ext_vector_type(4))) float f32x4;

__device__ __forceinline__ short f2bf(float f) {
  unsigned int u = __float_as_uint(f);
  unsigned int r = (u + 0x7FFFu + ((u >> 16) & 1u)) >> 16;
  return (short)(r & 0xFFFFu);
}

__device__ __forceinline__ bf16x8 cvt8(const float* src) {
  float4 u0 = *reinterpret_cast<const float4*>(src);
  float4 u1 = *reinterpret_cast<const float4*>(src + 4);
  return (bf16x8){f2bf(u0.x), f2bf(u0.y), f2bf(u0.z), f2bf(u0.w),
                  f2bf(u1.x), f2bf(u1.y), f2bf(u1.z), f2bf(u1.w)};
}

// ---------------- K1: partial histograms + fragment-ordered weight conversion ----------------

__global__ __launch_bounds__(256) void prep_kernel(
    const int* __restrict__ bidx,
    const float* __restrict__ kls0, const float* __restrict__ kls1,
    const float* __restrict__ kls2,
    int* __restrict__ partial, short* __restrict__ wb)
{
  int b = blockIdx.x;
  int tid = threadIdx.x;
  if (b < 64) {
    __shared__ int lh[NSCENE];
    if (tid < NSCENE) lh[tid] = 0;
    __syncthreads();
    atomicAdd(&lh[bidx[b * 256 + tid]], 1);
    __syncthreads();
    if (tid < NSCENE) partial[b * 64 + tid] = lh[tid];
  } else {
    int e = ((b - 64) * 256 + tid) * 8;   // output elem index (8 shorts/thread)
    if (e < WTOT) {
      const float* src;
      if (e < W0_ELEMS) {
        int s = e >> 15, r = e & 32767;
        int w = r >> 12, ks = (r >> 9) & 7, l = (r >> 3) & 63;
        int row = w * 16 + (l & 15), k = ks * 32 + (l >> 4) * 8;
        src = kls0 + ((size_t)s << 15) + row * SIN + k;
      } else if (e < W0_ELEMS + W1_ELEMS) {
        int e1 = e - W0_ELEMS;
        int s = e1 >> 14, r = e1 & 16383;
        int w = r >> 11, ks = (r >> 9) & 3, l = (r >> 3) & 63;
        int row = w * 16 + (l & 15), k = ks * 32 + (l >> 4) * 8;
        src = kls1 + ((size_t)s << 14) + row * SH + k;
      } else {
        int e2 = e - W0_ELEMS - W1_ELEMS;
        int s = e2 >> 15, r = e2 & 32767;
        int w = r >> 12, ks = (r >> 9) & 7, l = (r >> 3) & 63;
        int row = w * 16 + (l & 15), k = ks * 32 + (l >> 4) * 8;
        src = kls2 + ((size_t)s << 15) + row * SIN + k;
      }
      *reinterpret_cast<bf16x8*>(wb + e) = cvt8(src);   // coalesced write
    }
  }
}

// ---------------- K2: scan + scatter (R2-proven) ----------------

__global__ __launch_bounds__(256) void scatter_kernel(
    const int* __restrict__ bidx, const int* __restrict__ partial,
    int* __restrict__ offsets, int* __restrict__ perm)
{
  __shared__ int cur[NSCENE];
  int b = blockIdx.x;
  int tid = threadIdx.x;
  if (tid < 64) {
    int s = tid;
    int colpre = 0, total = 0;
    for (int bb = 0; bb < 64; ++bb) {
      int v = partial[bb * 64 + s];
      if (bb < b) colpre += v;
      total += v;
    }
    int v = total;
    for (int off = 1; off < 64; off <<= 1) {
      int t = __shfl_up(v, off);
      if (s >= off) v += t;
    }
    int sceneoff = v - total;
    cur[s] = sceneoff + colpre;
    if (b == 0) {
      offsets[s] = sceneoff;
      if (s == 63) offsets[64] = NPTS;
    }
  }
  __syncthreads();
  int n = b * 256 + tid;
  int s = bidx[n];
  int pos = atomicAdd(&cur[s], 1);
  perm[pos] = n;
}

// ---------------- K3: fused GEMM, ALL weight fragments register-resident ----------------
// grid 512: bid = t0*64 + s (scene pinned to XCD bid%8 == s%8).
// 512 threads = 8 waves; wave w owns output cols [w*16, w*16+16), tile = 32 points.
// Tile loop has ZERO weight VMEM: only perm/x loads and out stores.

__global__ __launch_bounds__(512) void fused_kernel(
    const float* __restrict__ bias0, const float* __restrict__ bias1,
    const float* __restrict__ x,
    const int* __restrict__ offsets, const int* __restrict__ perm,
    const short* __restrict__ wb, float* __restrict__ out)
{
  __shared__ __align__(16) short xr[TILE_P][SIN + 8];   // relu(x) bf16
  __shared__ __align__(16) short xp[TILE_P][SIN + 8];   // x bf16
  __shared__ __align__(16) short snet[TILE_P][SH + 8];  // relu(net) bf16
  __shared__ int ptile[TILE_P];

  const int s    = blockIdx.x & 63;
  const int t0   = blockIdx.x >> 6;
  const int base = offsets[s];
  const int cnt  = offsets[s + 1] - base;
  const int tid  = threadIdx.x;
  const int lane = tid & 63;
  const int w    = tid >> 6;            // 0..7
  const int l15  = lane & 15;
  const int lh4  = lane >> 4;
  const int col  = w * 16 + l15;

  // fragment-ordered weight bases (coalesced: lane*16B within each 1KB frag)
  const short* B0s = wb + ((size_t)s << 15) + (w << 12) + (lane << 3);
  const short* B1s = wb + W0_ELEMS + ((size_t)s << 14) + (w << 11) + (lane << 3);
  const short* B2s = wb + W0_ELEMS + W1_ELEMS + ((size_t)s << 15) + (w << 12) + (lane << 3);

  const float bv0 = bias0[(size_t)s * SH + col];
  const float bv1 = bias1[(size_t)s * SOUT + col];

  // ---- preload ALL weight fragments into registers (one burst, 20 loads) ----
  bf16x8 b0c[8], b2c[8], b1c[4];
#pragma unroll
  for (int ks = 0; ks < 8; ++ks) {
    b0c[ks] = *reinterpret_cast<const bf16x8*>(B0s + (ks << 9));
    b2c[ks] = *reinterpret_cast<const bf16x8*>(B2s + (ks << 9));
  }
#pragma unroll
  for (int ks = 0; ks < 4; ++ks)
    b1c[ks] = *reinterpret_cast<const bf16x8*>(B1s + (ks << 9));

  for (int t = t0; t * TILE_P < cnt; t += 8) {
    __syncthreads();  // protect LDS reuse across tile iterations

    // ---- stage x tile: 16 threads per row, 16 floats each ----
    {
      int r  = tid >> 4;
      int cg = tid & 15;
      int prow = t * TILE_P + r;
      int np = (prow < cnt) ? perm[base + prow] : -1;
      if (cg == 0) ptile[r] = np;
      const float* xrow = x + (size_t)(np < 0 ? 0 : np) * SIN;
      int c0 = cg * 16;
      for (int j = 0; j < 16; j += 4) {
        float4 v = make_float4(0.f, 0.f, 0.f, 0.f);
        if (np >= 0) v = *reinterpret_cast<const float4*>(xrow + c0 + j);
        short4 p, q;
        p.x = f2bf(v.x); p.y = f2bf(v.y); p.z = f2bf(v.z); p.w = f2bf(v.w);
        q.x = f2bf(fmaxf(v.x, 0.f)); q.y = f2bf(fmaxf(v.y, 0.f));
        q.z = f2bf(fmaxf(v.z, 0.f)); q.w = f2bf(fmaxf(v.w, 0.f));
        *reinterpret_cast<short4*>(&xp[r][c0 + j]) = p;
        *reinterpret_cast<short4*>(&xr[r][c0 + j]) = q;
      }
    }
    __syncthreads();

    // ---- layers 0 + 2: pure LDS + MFMA ----
    f32x4 acc0[2], acc[2];
#pragma unroll
    for (int mt = 0; mt < 2; ++mt) {
      acc0[mt] = (f32x4){bv0, bv0, bv0, bv0};
      acc[mt]  = (f32x4){bv1, bv1, bv1, bv1};
    }
#pragma unroll
    for (int ks = 0; ks < 8; ++ks) {
      int kc = ks * 32 + lh4 * 8;
#pragma unroll
      for (int mt = 0; mt < 2; ++mt) {
        bf16x8 aR = *reinterpret_cast<const bf16x8*>(&xr[mt * 16 + l15][kc]);
        bf16x8 aP = *reinterpret_cast<const bf16x8*>(&xp[mt * 16 + l15][kc]);
        acc0[mt] = __builtin_amdgcn_mfma_f32_16x16x32_bf16(aR, b0c[ks], acc0[mt], 0, 0, 0);
        acc[mt]  = __builtin_amdgcn_mfma_f32_16x16x32_bf16(aP, b2c[ks], acc[mt],  0, 0, 0);
      }
    }

    // write relu(net) -> LDS (D layout: row=(lane>>4)*4+reg, col=lane&15)
#pragma unroll
    for (int mt = 0; mt < 2; ++mt)
#pragma unroll
      for (int r4 = 0; r4 < 4; ++r4)
        snet[mt * 16 + lh4 * 4 + r4][col] = f2bf(fmaxf(acc0[mt][r4], 0.f));
    __syncthreads();  // snet ready

    // ---- layer 1: acc += relu(net) @ W1^T (weights in registers) ----
#pragma unroll
    for (int ks = 0; ks < 4; ++ks) {
      int kc = ks * 32 + lh4 * 8;
#pragma unroll
      for (int mt = 0; mt < 2; ++mt) {
        bf16x8 aS = *reinterpret_cast<const bf16x8*>(&snet[mt * 16 + l15][kc]);
        acc[mt] = __builtin_amdgcn_mfma_f32_16x16x32_bf16(aS, b1c[ks], acc[mt], 0, 0, 0);
      }
    }

    // ---- store ----
#pragma unroll
    for (int mt = 0; mt < 2; ++mt)
#pragma unroll
      for (int r4 = 0; r4 < 4; ++r4) {
        int row = mt * 16 + lh4 * 4 + r4;
        int pt = ptile[row];
        if (pt >= 0) out[(size_t)pt * SOUT + col] = acc[mt][r4];
      }
  }
}

// ---------------- launch ----------------

extern "C" void kernel_launch(void* const* d_in, const int* in_sizes, int n_in,
                              void* d_out, int out_size, void* d_ws, size_t ws_size,
                              hipStream_t stream) {
  const float* kls0  = (const float*)d_in[0];
  const float* kls1  = (const float*)d_in[1];
  const float* kls2  = (const float*)d_in[2];
  const float* bias0 = (const float*)d_in[3];
  const float* bias1 = (const float*)d_in[4];
  const float* x     = (const float*)d_in[5];
  const int*   bidx  = (const int*)d_in[6];
  float* out = (float*)d_out;

  int*   partial = (int*)((char*)d_ws + WS_PARTIAL);
  int*   offsets = (int*)((char*)d_ws + WS_OFFSETS);
  int*   perm    = (int*)((char*)d_ws + WS_PERM);
  short* wb      = (short*)((char*)d_ws + WS_WBF16);

  prep_kernel<<<64 + CONV_BLOCKS, 256, 0, stream>>>(
      bidx, kls0, kls1, kls2, partial, wb);
  scatter_kernel<<<64, 256, 0, stream>>>(bidx, partial, offsets, perm);
  fused_kernel<<<512, 512, 0, stream>>>(bias0, bias1, x, offsets, perm, wb, out);
}